// Round 3
// baseline (541.154 us; speedup 1.0000x reference)
//
#include <hip/hip_runtime.h>
#include <cstdint>
#include <cstddef>

constexpr int Bn = 64, Tn = 1024, Hn = 256, Kn = 4;
constexpr int MROWS = 32;           // output t-rows per block
constexpr int SROWS = MROWS + 2;    // staged input rows
constexpr int SST   = 36;           // LDS row stride (16B-aligned, 34 used)
constexpr int CHI   = 4;            // i-values per B chunk
constexpr int NCH   = Hn / CHI;     // 64 chunks

// Pack conv_w [o][i][dt] -> wP[(dt*256+i)][o]
__global__ __launch_bounds__(256) void pack_w_k(const float* __restrict__ conv_w,
                                                float* __restrict__ wP) {
  int o  = threadIdx.x;
  int kk = blockIdx.x;              // kk = dt*256 + i
  int dt = kk >> 8, i = kk & 255;
  wP[kk * Hn + o] = conv_w[o * (Hn * 3) + i * 3 + dt];
}

// Fused conv1d(k=3,pad=1) + bias + ReLU + Linear(256->4): em[B,T,4] fp32
// C-tile 32(t) x 256(n); A transposed in LDS; B single-buffered 4-i chunks
// with register prefetch (issue-early / write-late). Lane n-cols remapped to
// two quads {ng*4..+3, 128+ng*4..+3} so both ds_read_b128 are conflict-free.
__global__ __launch_bounds__(256, 3) void emis_k(const float* __restrict__ x,
    const float* __restrict__ wP, const float* __restrict__ conv_b,
    const float* __restrict__ lin_w, const float* __restrict__ lin_b,
    float* __restrict__ em) {
  __shared__ float xsT[Hn * SST];        // [i][row], 36,864 B
  __shared__ float bufB[3 * CHI][Hn];    // 12,288 B  (total 49,152 -> 3 blk/CU)

  const int b  = blockIdx.y, t0 = blockIdx.x * MROWS;
  const int tid = threadIdx.x;
  const int ng = tid & 31;          // n-group: quads at ng*4 and 128+ng*4
  const int mg = tid >> 5;          // m-group: rows 4*mg .. +3

  // ---- Stage A transposed: [i][row], rows = t0-1 .. t0+32 ----
  const float4* x4 = reinterpret_cast<const float4*>(x + (size_t)b * Tn * Hn);
  for (int idx = tid; idx < SROWS * (Hn / 4); idx += 256) {
    int row = idx >> 6, c4 = idx & 63;
    int t = t0 - 1 + row;
    float4 v = make_float4(0.f, 0.f, 0.f, 0.f);
    if (t >= 0 && t < Tn) v = x4[t * (Hn / 4) + c4];
    int i = c4 << 2;
    xsT[(i + 0) * SST + row] = v.x;
    xsT[(i + 1) * SST + row] = v.y;
    xsT[(i + 2) * SST + row] = v.z;
    xsT[(i + 3) * SST + row] = v.w;
  }

  // ---- B prologue: write chunk 0, prefetch chunk 1 into regs ----
  const float4* w4 = reinterpret_cast<const float4*>(wP);
  const int h = tid >> 6, c4v = tid & 63;   // rows dt*4+h, lane col c4v
  float4 p0 = w4[(0 * 256 + 0 + h) * 64 + c4v];
  float4 p1 = w4[(1 * 256 + 0 + h) * 64 + c4v];
  float4 p2 = w4[(2 * 256 + 0 + h) * 64 + c4v];
  *reinterpret_cast<float4*>(&bufB[0 + h][c4v * 4]) = p0;
  *reinterpret_cast<float4*>(&bufB[4 + h][c4v * 4]) = p1;
  *reinterpret_cast<float4*>(&bufB[8 + h][c4v * 4]) = p2;
  p0 = w4[(0 * 256 + CHI + h) * 64 + c4v];
  p1 = w4[(1 * 256 + CHI + h) * 64 + c4v];
  p2 = w4[(2 * 256 + CHI + h) * 64 + c4v];
  __syncthreads();

  float acc[4][8];
  #pragma unroll
  for (int rr = 0; rr < 4; ++rr)
    #pragma unroll
    for (int j = 0; j < 8; ++j) acc[rr][j] = 0.f;

  #pragma unroll 1
  for (int c = 0; c < NCH; ++c) {
    #pragma unroll
    for (int ii = 0; ii < CHI; ++ii) {
      const int i = c * CHI + ii;
      const float* ap = &xsT[i * SST + 4 * mg];
      const float4 a01 = *reinterpret_cast<const float4*>(ap);
      const float2 a2  = *reinterpret_cast<const float2*>(ap + 4);
      const float a[6] = {a01.x, a01.y, a01.z, a01.w, a2.x, a2.y};
      #pragma unroll
      for (int dt = 0; dt < 3; ++dt) {
        const float* bp = &bufB[dt * 4 + ii][ng * 4];
        const float4 b0 = *reinterpret_cast<const float4*>(bp);        // cols ng*4..+3
        const float4 b1 = *reinterpret_cast<const float4*>(bp + 128);  // cols 128+ng*4..+3
        const float bb[8] = {b0.x, b0.y, b0.z, b0.w, b1.x, b1.y, b1.z, b1.w};
        #pragma unroll
        for (int rr = 0; rr < 4; ++rr)
          #pragma unroll
          for (int j = 0; j < 8; ++j)
            acc[rr][j] = fmaf(a[rr + dt], bb[j], acc[rr][j]);
      }
    }
    if (c + 1 < NCH) {
      __syncthreads();                 // everyone done reading bufB chunk c
      *reinterpret_cast<float4*>(&bufB[0 + h][c4v * 4]) = p0;
      *reinterpret_cast<float4*>(&bufB[4 + h][c4v * 4]) = p1;
      *reinterpret_cast<float4*>(&bufB[8 + h][c4v * 4]) = p2;
      if (c + 2 < NCH) {               // issue-early: hides under compute(c+1)
        const int i0 = (c + 2) * CHI;
        p0 = w4[(0 * 256 + i0 + h) * 64 + c4v];
        p1 = w4[(1 * 256 + i0 + h) * 64 + c4v];
        p2 = w4[(2 * 256 + i0 + h) * 64 + c4v];
      }
      __syncthreads();                 // chunk c+1 visible
    }
  }

  // ---- Epilogue: +conv_b, ReLU, x lin_w^T, reduce over 32 ng lanes ----
  float pem[4][4];
  #pragma unroll
  for (int rr = 0; rr < 4; ++rr)
    #pragma unroll
    for (int k = 0; k < 4; ++k) pem[rr][k] = 0.f;

  #pragma unroll
  for (int j = 0; j < 8; ++j) {
    const int n = (j < 4) ? (ng * 4 + j) : (128 + ng * 4 + (j - 4));
    const float cb = conv_b[n];
    const float l0 = lin_w[0 * Hn + n];
    const float l1 = lin_w[1 * Hn + n];
    const float l2 = lin_w[2 * Hn + n];
    const float l3 = lin_w[3 * Hn + n];
    #pragma unroll
    for (int rr = 0; rr < 4; ++rr) {
      float v = fmaxf(acc[rr][j] + cb, 0.f);
      pem[rr][0] = fmaf(v, l0, pem[rr][0]);
      pem[rr][1] = fmaf(v, l1, pem[rr][1]);
      pem[rr][2] = fmaf(v, l2, pem[rr][2]);
      pem[rr][3] = fmaf(v, l3, pem[rr][3]);
    }
  }
  #pragma unroll
  for (int rr = 0; rr < 4; ++rr)
    #pragma unroll
    for (int k = 0; k < 4; ++k) {
      float v = pem[rr][k];
      v += __shfl_xor(v, 1);
      v += __shfl_xor(v, 2);
      v += __shfl_xor(v, 4);
      v += __shfl_xor(v, 8);
      v += __shfl_xor(v, 16);
      pem[rr][k] = v;
    }
  if (ng == 0) {
    #pragma unroll
    for (int rr = 0; rr < 4; ++rr) {
      const int m = 4 * mg + rr;
      float4 o;
      o.x = pem[rr][0] + lin_b[0];
      o.y = pem[rr][1] + lin_b[1];
      o.z = pem[rr][2] + lin_b[2];
      o.w = pem[rr][3] + lin_b[3];
      *reinterpret_cast<float4*>(em + (size_t)(b * Tn + t0 + m) * 4) = o;
    }
  }
}

// byte-map composition c(k) = a(b(k))
__device__ __forceinline__ unsigned int compose_map(unsigned int a, unsigned int b) {
#if __has_builtin(__builtin_amdgcn_perm)
  return __builtin_amdgcn_perm(a, a, b);
#else
  unsigned int c = 0;
  #pragma unroll
  for (int k = 0; k < 4; ++k) {
    unsigned int sel = (b >> (8 * k)) & 0xffu;
    c |= ((a >> (8 * sel)) & 0xffu) << (8 * k);
  }
  return c;
#endif
}

// CRF Viterbi decode. Forward: serial max-only scan on lane 0 (bitwise-
// identical candidate math to ref). Backtrace: 64 lanes rebuild argmax maps,
// compose via v_perm suffix-scan (integer-exact).
__global__ __launch_bounds__(64) void viterbi_k(const float* __restrict__ em,
    const float* __restrict__ cstart, const float* __restrict__ cend,
    const float* __restrict__ ctrans, int* __restrict__ out) {
  __shared__ float4 se[Tn];          // emissions, 16 KB
  __shared__ float4 sh[Tn - 1];      // score vector BEFORE step t+1, 16 KB
  __shared__ int s_last;
  const int b = blockIdx.x, lane = threadIdx.x;
  const float4* e4 = reinterpret_cast<const float4*>(em + (size_t)b * Tn * Kn);
  for (int i = lane; i < Tn; i += 64) se[i] = e4[i];
  float tr[4][4];
  #pragma unroll
  for (int j = 0; j < 4; ++j)
    #pragma unroll
    for (int k = 0; k < 4; ++k) tr[j][k] = ctrans[j * 4 + k];
  __syncthreads();

  if (lane == 0) {
    float4 e0 = se[0];
    float s0 = cstart[0] + e0.x, s1 = cstart[1] + e0.y;
    float s2 = cstart[2] + e0.z, s3 = cstart[3] + e0.w;
    float4 eA = se[1], eB = se[2];
    for (int t = 1; t < Tn; ++t) {
      const float4 e = eA;
      eA = eB;
      if (t + 2 < Tn) eB = se[t + 2];
      sh[t - 1] = make_float4(s0, s1, s2, s3);
      const float ev[4] = {e.x, e.y, e.z, e.w};
      float ns[4];
      #pragma unroll
      for (int k = 0; k < 4; ++k) {
        float m01 = fmaxf((s0 + tr[0][k]) + ev[k], (s1 + tr[1][k]) + ev[k]);
        float m23 = fmaxf((s2 + tr[2][k]) + ev[k], (s3 + tr[3][k]) + ev[k]);
        ns[k] = fmaxf(m01, m23);
      }
      s0 = ns[0]; s1 = ns[1]; s2 = ns[2]; s3 = ns[3];
    }
    s0 += cend[0]; s1 += cend[1]; s2 += cend[2]; s3 += cend[3];
    int tag = 0; float bf = s0;
    if (s1 > bf) { bf = s1; tag = 1; }
    if (s2 > bf) { bf = s2; tag = 2; }
    if (s3 > bf) { bf = s3; tag = 3; }
    s_last = tag;
  }
  __syncthreads();

  // ---- parallel backtrace: lane owns maps t in [16*lane, 16*lane+15] ----
  const unsigned int ID = 0x03020100u;
  unsigned int mloc[16];
  const int t0 = lane * 16;
  #pragma unroll
  for (int k = 0; k < 16; ++k) {
    const int t = t0 + k;
    if (t < Tn - 1) {
      const float4 s = sh[t];
      const float4 e = se[t + 1];
      const float sj[4] = {s.x, s.y, s.z, s.w};
      const float ev[4] = {e.x, e.y, e.z, e.w};
      unsigned int mw = 0;
      #pragma unroll
      for (int kk = 0; kk < 4; ++kk) {
        float best = (sj[0] + tr[0][kk]) + ev[kk];
        int bi = 0;
        #pragma unroll
        for (int j = 1; j < 4; ++j) {
          float cc = (sj[j] + tr[j][kk]) + ev[kk];
          if (cc > best) { best = cc; bi = j; }
        }
        mw |= (unsigned)bi << (8 * kk);
      }
      mloc[k] = mw;
    } else {
      mloc[k] = ID;
    }
  }
  unsigned int P = mloc[15];
  #pragma unroll
  for (int k = 14; k >= 0; --k) P = compose_map(mloc[k], P);
  #pragma unroll
  for (int d = 1; d < 64; d <<= 1) {
    unsigned int q = (unsigned int)__shfl_down((int)P, d);
    if (lane + d > 63) q = ID;
    P = compose_map(P, q);
  }
  unsigned int E = (unsigned int)__shfl_down((int)P, 1);  // exclusive suffix
  if (lane == 63) E = ID;
  const int last = s_last;
  unsigned int tag = (E >> (8 * last)) & 3u;
  int* ob = out + (size_t)b * Tn;
  #pragma unroll
  for (int k = 15; k >= 0; --k) {
    tag = (mloc[k] >> (8 * tag)) & 3u;
    ob[t0 + k] = (int)tag;
  }
}

extern "C" void kernel_launch(void* const* d_in, const int* in_sizes, int n_in,
                              void* d_out, int out_size, void* d_ws, size_t ws_size,
                              hipStream_t stream) {
  const float* x      = (const float*)d_in[0];
  const float* conv_w = (const float*)d_in[1];
  const float* conv_b = (const float*)d_in[2];
  const float* lin_w  = (const float*)d_in[3];
  const float* lin_b  = (const float*)d_in[4];
  const float* cstart = (const float*)d_in[5];
  const float* cend   = (const float*)d_in[6];
  const float* ctrans = (const float*)d_in[7];
  int* out = (int*)d_out;

  float* wP = (float*)d_ws;                      // 768*256 floats
  float* em = wP + 768 * 256;                    // 64*1024*4 floats

  pack_w_k<<<768, 256, 0, stream>>>(conv_w, wP);
  emis_k<<<dim3(Tn / MROWS, Bn), 256, 0, stream>>>(x, wP, conv_b, lin_w, lin_b, em);
  viterbi_k<<<Bn, 64, 0, stream>>>(em, cstart, cend, ctrans, out);
}

// Round 4
// 440.905 us; speedup vs baseline: 1.2274x; 1.2274x over previous
//
#include <hip/hip_runtime.h>
#include <cstdint>
#include <cstddef>

constexpr int Bn = 64, Tn = 1024, Hn = 256, Kn = 4;
constexpr int MROWS = 32;           // output t-rows per block
constexpr int SROWS = MROWS + 2;    // staged input rows
constexpr int SST   = 36;           // LDS row stride (16B-aligned, 34 used)
constexpr int CHI   = 4;            // i-values per B chunk
constexpr int NCH   = Hn / CHI;     // 64 chunks

// Pack conv_w [o][i][dt] -> wP[(dt*256+i)][o]
__global__ __launch_bounds__(256) void pack_w_k(const float* __restrict__ conv_w,
                                                float* __restrict__ wP) {
  int o  = threadIdx.x;
  int kk = blockIdx.x;              // kk = dt*256 + i
  int dt = kk >> 8, i = kk & 255;
  wP[kk * Hn + o] = conv_w[o * (Hn * 3) + i * 3 + dt];
}

// Fused conv1d(k=3,pad=1) + bias + ReLU + Linear(256->4): em[B,T,4] fp32.
// Round-2 pipeline (double-buffered B chunks, ONE barrier per chunk,
// issue-early/write-late register prefetch, bound (256,2) -> no spill)
// + round-3 conflict-free B-read mapping (lane ng reads quads ng*4 and
// 128+ng*4: consecutive lanes -> consecutive 16B -> conflict-free).
__global__ __launch_bounds__(256, 2) void emis_k(const float* __restrict__ x,
    const float* __restrict__ wP, const float* __restrict__ conv_b,
    const float* __restrict__ lin_w, const float* __restrict__ lin_b,
    float* __restrict__ em) {
  __shared__ float xsT[Hn * SST];        // [i][row], 36,864 B
  __shared__ float bufB[2][3 * CHI][Hn]; // 24,576 B (total 61,440 -> 2 blk/CU)

  const int b  = blockIdx.y, t0 = blockIdx.x * MROWS;
  const int tid = threadIdx.x;
  const int ng = tid & 31;          // n-group: quads at ng*4 and 128+ng*4
  const int mg = tid >> 5;          // m-group: rows 4*mg .. +3

  // ---- Stage A transposed: [i][row], rows = t0-1 .. t0+32 ----
  const float4* x4 = reinterpret_cast<const float4*>(x + (size_t)b * Tn * Hn);
  for (int idx = tid; idx < SROWS * (Hn / 4); idx += 256) {
    int row = idx >> 6, c4 = idx & 63;
    int t = t0 - 1 + row;
    float4 v = make_float4(0.f, 0.f, 0.f, 0.f);
    if (t >= 0 && t < Tn) v = x4[t * (Hn / 4) + c4];
    int i = c4 << 2;
    xsT[(i + 0) * SST + row] = v.x;
    xsT[(i + 1) * SST + row] = v.y;
    xsT[(i + 2) * SST + row] = v.z;
    xsT[(i + 3) * SST + row] = v.w;
  }

  // ---- Stage B chunk 0 ----
  const float4* w4 = reinterpret_cast<const float4*>(wP);
  const int h = tid >> 6, c4v = tid & 63;   // rows dt*4+h, lane col c4v
  float4 pre0 = w4[(0 * 256 + 0 + h) * 64 + c4v];
  float4 pre1 = w4[(1 * 256 + 0 + h) * 64 + c4v];
  float4 pre2 = w4[(2 * 256 + 0 + h) * 64 + c4v];
  *reinterpret_cast<float4*>(&bufB[0][0 + h][c4v * 4]) = pre0;
  *reinterpret_cast<float4*>(&bufB[0][4 + h][c4v * 4]) = pre1;
  *reinterpret_cast<float4*>(&bufB[0][8 + h][c4v * 4]) = pre2;
  __syncthreads();

  float acc[4][8];
  #pragma unroll
  for (int rr = 0; rr < 4; ++rr)
    #pragma unroll
    for (int j = 0; j < 8; ++j) acc[rr][j] = 0.f;

  #pragma unroll 1
  for (int c = 0; c < NCH; ++c) {
    const int cur = c & 1;
    const bool more = (c + 1 < NCH);
    if (more) {   // issue next-chunk global loads early (hide L2 latency)
      const int i0n = (c + 1) * CHI;
      pre0 = w4[(0 * 256 + i0n + h) * 64 + c4v];
      pre1 = w4[(1 * 256 + i0n + h) * 64 + c4v];
      pre2 = w4[(2 * 256 + i0n + h) * 64 + c4v];
    }
    #pragma unroll
    for (int ii = 0; ii < CHI; ++ii) {
      const int i = c * CHI + ii;
      const float* ap = &xsT[i * SST + 4 * mg];
      const float4 a01 = *reinterpret_cast<const float4*>(ap);
      const float2 a2  = *reinterpret_cast<const float2*>(ap + 4);
      const float a[6] = {a01.x, a01.y, a01.z, a01.w, a2.x, a2.y};
      #pragma unroll
      for (int dt = 0; dt < 3; ++dt) {
        const float* bp = &bufB[cur][dt * 4 + ii][ng * 4];
        const float4 b0 = *reinterpret_cast<const float4*>(bp);        // cols ng*4..+3
        const float4 b1 = *reinterpret_cast<const float4*>(bp + 128);  // cols 128+ng*4..+3
        const float bb[8] = {b0.x, b0.y, b0.z, b0.w, b1.x, b1.y, b1.z, b1.w};
        #pragma unroll
        for (int rr = 0; rr < 4; ++rr)
          #pragma unroll
          for (int j = 0; j < 8; ++j)
            acc[rr][j] = fmaf(a[rr + dt], bb[j], acc[rr][j]);
      }
    }
    if (more) {   // write-late: staged after compute, before barrier
      *reinterpret_cast<float4*>(&bufB[cur ^ 1][0 + h][c4v * 4]) = pre0;
      *reinterpret_cast<float4*>(&bufB[cur ^ 1][4 + h][c4v * 4]) = pre1;
      *reinterpret_cast<float4*>(&bufB[cur ^ 1][8 + h][c4v * 4]) = pre2;
    }
    __syncthreads();
  }

  // ---- Epilogue: +conv_b, ReLU, x lin_w^T, reduce over 32 ng lanes ----
  float pem[4][4];
  #pragma unroll
  for (int rr = 0; rr < 4; ++rr)
    #pragma unroll
    for (int k = 0; k < 4; ++k) pem[rr][k] = 0.f;

  #pragma unroll
  for (int j = 0; j < 8; ++j) {
    const int n = (j < 4) ? (ng * 4 + j) : (128 + ng * 4 + (j - 4));
    const float cb = conv_b[n];
    const float l0 = lin_w[0 * Hn + n];
    const float l1 = lin_w[1 * Hn + n];
    const float l2 = lin_w[2 * Hn + n];
    const float l3 = lin_w[3 * Hn + n];
    #pragma unroll
    for (int rr = 0; rr < 4; ++rr) {
      float v = fmaxf(acc[rr][j] + cb, 0.f);
      pem[rr][0] = fmaf(v, l0, pem[rr][0]);
      pem[rr][1] = fmaf(v, l1, pem[rr][1]);
      pem[rr][2] = fmaf(v, l2, pem[rr][2]);
      pem[rr][3] = fmaf(v, l3, pem[rr][3]);
    }
  }
  #pragma unroll
  for (int rr = 0; rr < 4; ++rr)
    #pragma unroll
    for (int k = 0; k < 4; ++k) {
      float v = pem[rr][k];
      v += __shfl_xor(v, 1);
      v += __shfl_xor(v, 2);
      v += __shfl_xor(v, 4);
      v += __shfl_xor(v, 8);
      v += __shfl_xor(v, 16);
      pem[rr][k] = v;
    }
  if (ng == 0) {
    #pragma unroll
    for (int rr = 0; rr < 4; ++rr) {
      const int m = 4 * mg + rr;
      float4 o;
      o.x = pem[rr][0] + lin_b[0];
      o.y = pem[rr][1] + lin_b[1];
      o.z = pem[rr][2] + lin_b[2];
      o.w = pem[rr][3] + lin_b[3];
      *reinterpret_cast<float4*>(em + (size_t)(b * Tn + t0 + m) * 4) = o;
    }
  }
}

// byte-map composition c(k) = a(b(k))
__device__ __forceinline__ unsigned int compose_map(unsigned int a, unsigned int b) {
#if __has_builtin(__builtin_amdgcn_perm)
  return __builtin_amdgcn_perm(a, a, b);
#else
  unsigned int c = 0;
  #pragma unroll
  for (int k = 0; k < 4; ++k) {
    unsigned int sel = (b >> (8 * k)) & 0xffu;
    c |= ((a >> (8 * sel)) & 0xffu) << (8 * k);
  }
  return c;
#endif
}

// One Viterbi step. Value math: ns_k = (max_j (s_j + tr[j][k])) + e_k.
// Bitwise-identical to the reference's max_j((s_j+tr)+e) because fp rounding
// is monotone (a>=b => fl(a+c)>=fl(b+c)); fmax tree == sequential max
// (max is associative on the VALUES). Argmax is NOT taken here (backtrace
// recomputes the exact per-candidate (s+tr)+e form with first-wins ties).
#define VSTEP(EV, T)                                                        \
  {                                                                         \
    sh[(T) - 1] = make_float4(s0, s1, s2, s3);                              \
    const float4 e_ = (EV);                                                 \
    float x0 = fmaxf(fmaxf(s0 + tr[0][0], s1 + tr[1][0]),                   \
                     fmaxf(s2 + tr[2][0], s3 + tr[3][0]));                  \
    float x1 = fmaxf(fmaxf(s0 + tr[0][1], s1 + tr[1][1]),                   \
                     fmaxf(s2 + tr[2][1], s3 + tr[3][1]));                  \
    float x2 = fmaxf(fmaxf(s0 + tr[0][2], s1 + tr[1][2]),                   \
                     fmaxf(s2 + tr[2][2], s3 + tr[3][2]));                  \
    float x3 = fmaxf(fmaxf(s0 + tr[0][3], s1 + tr[1][3]),                   \
                     fmaxf(s2 + tr[2][3], s3 + tr[3][3]));                  \
    s0 = x0 + e_.x; s1 = x1 + e_.y; s2 = x2 + e_.z; s3 = x3 + e_.w;         \
  }

// CRF Viterbi decode. Forward: serial scan on lane 0, 4x-unrolled with
// 4-deep register prefetch of emissions (covers ~120cy LDS latency).
// Backtrace: 64 lanes rebuild argmax maps, compose via v_perm suffix-scan.
__global__ __launch_bounds__(64) void viterbi_k(const float* __restrict__ em,
    const float* __restrict__ cstart, const float* __restrict__ cend,
    const float* __restrict__ ctrans, int* __restrict__ out) {
  __shared__ float4 se[Tn];          // emissions, 16 KB
  __shared__ float4 sh[Tn - 1];      // score vector BEFORE step t+1, 16 KB
  __shared__ int s_last;
  const int b = blockIdx.x, lane = threadIdx.x;
  const float4* e4 = reinterpret_cast<const float4*>(em + (size_t)b * Tn * Kn);
  for (int i = lane; i < Tn; i += 64) se[i] = e4[i];
  float tr[4][4];
  #pragma unroll
  for (int j = 0; j < 4; ++j)
    #pragma unroll
    for (int k = 0; k < 4; ++k) tr[j][k] = ctrans[j * 4 + k];
  __syncthreads();

  if (lane == 0) {
    float4 e0 = se[0];
    float s0 = cstart[0] + e0.x, s1 = cstart[1] + e0.y;
    float s2 = cstart[2] + e0.z, s3 = cstart[3] + e0.w;
    float4 eA = se[1], eB = se[2], eC = se[3], eD = se[4];
    // main loop: t = 1..1020 in steps of 4 (255 iterations)
    for (int t = 1; t + 3 < Tn; t += 4) {
      const float4 f0 = eA, f1 = eB, f2 = eC, f3 = eD;
      if (t + 4 < Tn) eA = se[t + 4];
      if (t + 5 < Tn) eB = se[t + 5];
      if (t + 6 < Tn) eC = se[t + 6];
      if (t + 7 < Tn) eD = se[t + 7];
      VSTEP(f0, t);
      VSTEP(f1, t + 1);
      VSTEP(f2, t + 2);
      VSTEP(f3, t + 3);
    }
    // tail: t = 1021, 1022, 1023 (eA..eC hold se[1021..1023])
    VSTEP(eA, Tn - 3);
    VSTEP(eB, Tn - 2);
    VSTEP(eC, Tn - 1);
    s0 += cend[0]; s1 += cend[1]; s2 += cend[2]; s3 += cend[3];
    int tag = 0; float bf = s0;
    if (s1 > bf) { bf = s1; tag = 1; }
    if (s2 > bf) { bf = s2; tag = 2; }
    if (s3 > bf) { bf = s3; tag = 3; }
    s_last = tag;
  }
  __syncthreads();

  // ---- parallel backtrace: lane owns maps t in [16*lane, 16*lane+15] ----
  const unsigned int ID = 0x03020100u;
  unsigned int mloc[16];
  const int t0 = lane * 16;
  #pragma unroll
  for (int k = 0; k < 16; ++k) {
    const int t = t0 + k;
    if (t < Tn - 1) {
      const float4 s = sh[t];
      const float4 e = se[t + 1];
      const float sj[4] = {s.x, s.y, s.z, s.w};
      const float ev[4] = {e.x, e.y, e.z, e.w};
      unsigned int mw = 0;
      #pragma unroll
      for (int kk = 0; kk < 4; ++kk) {
        float best = (sj[0] + tr[0][kk]) + ev[kk];
        int bi = 0;
        #pragma unroll
        for (int j = 1; j < 4; ++j) {
          float cc = (sj[j] + tr[j][kk]) + ev[kk];
          if (cc > best) { best = cc; bi = j; }
        }
        mw |= (unsigned)bi << (8 * kk);
      }
      mloc[k] = mw;
    } else {
      mloc[k] = ID;
    }
  }
  unsigned int P = mloc[15];
  #pragma unroll
  for (int k = 14; k >= 0; --k) P = compose_map(mloc[k], P);
  #pragma unroll
  for (int d = 1; d < 64; d <<= 1) {
    unsigned int q = (unsigned int)__shfl_down((int)P, d);
    if (lane + d > 63) q = ID;
    P = compose_map(P, q);
  }
  unsigned int E = (unsigned int)__shfl_down((int)P, 1);  // exclusive suffix
  if (lane == 63) E = ID;
  const int last = s_last;
  unsigned int tag = (E >> (8 * last)) & 3u;
  int* ob = out + (size_t)b * Tn;
  #pragma unroll
  for (int k = 15; k >= 0; --k) {
    tag = (mloc[k] >> (8 * tag)) & 3u;
    ob[t0 + k] = (int)tag;
  }
}

extern "C" void kernel_launch(void* const* d_in, const int* in_sizes, int n_in,
                              void* d_out, int out_size, void* d_ws, size_t ws_size,
                              hipStream_t stream) {
  const float* x      = (const float*)d_in[0];
  const float* conv_w = (const float*)d_in[1];
  const float* conv_b = (const float*)d_in[2];
  const float* lin_w  = (const float*)d_in[3];
  const float* lin_b  = (const float*)d_in[4];
  const float* cstart = (const float*)d_in[5];
  const float* cend   = (const float*)d_in[6];
  const float* ctrans = (const float*)d_in[7];
  int* out = (int*)d_out;

  float* wP = (float*)d_ws;                      // 768*256 floats
  float* em = wP + 768 * 256;                    // 64*1024*4 floats

  pack_w_k<<<768, 256, 0, stream>>>(conv_w, wP);
  emis_k<<<dim3(Tn / MROWS, Bn), 256, 0, stream>>>(x, wP, conv_b, lin_w, lin_b, em);
  viterbi_k<<<Bn, 64, 0, stream>>>(em, cstart, cend, ctrans, out);
}

// Round 5
// 409.120 us; speedup vs baseline: 1.3227x; 1.0777x over previous
//
#include <hip/hip_runtime.h>
#include <cstdint>
#include <cstddef>

constexpr int Bn = 64, Tn = 1024, Hn = 256, Kn = 4;
constexpr int MROWS = 32;           // output t-rows per block
constexpr int SROWS = MROWS + 2;    // staged input rows
constexpr int SST   = 36;           // LDS row stride (16B-aligned, 34 used)
constexpr int CHI   = 2;            // i-values per B chunk
constexpr int NCH   = Hn / CHI;     // 128 chunks

// Pack conv_w [o][i][dt] -> wP[(dt*256+i)][o]
__global__ __launch_bounds__(256) void pack_w_k(const float* __restrict__ conv_w,
                                                float* __restrict__ wP) {
  int o  = threadIdx.x;
  int kk = blockIdx.x;              // kk = dt*256 + i
  int dt = kk >> 8, i = kk & 255;
  wP[kk * Hn + o] = conv_w[o * (Hn * 3) + i * 3 + dt];
}

// Fused conv1d(k=3,pad=1) + bias + ReLU + Linear(256->4): em[B,T,4] fp32.
// Thread tile: 8 t-rows x 4 n-cols (lane ng4=tid&63 -> cols ng4*4..+3;
// wave mg=tid>>6 -> rows 8mg..+7). B LDS pressure = 64 B/cyc/CU (half of
// round-4's 128 = LDS peak). bufB CHI=2 double-buffered -> LDS 49,152 B
// -> 3 blocks/CU (12 waves) so barrier drains overlap across blocks.
__global__ __launch_bounds__(256, 2) void emis_k(const float* __restrict__ x,
    const float* __restrict__ wP, const float* __restrict__ conv_b,
    const float* __restrict__ lin_w, const float* __restrict__ lin_b,
    float* __restrict__ em) {
  __shared__ float xsT[Hn * SST];            // [chan][srow], 36,864 B
  __shared__ float bufB[2][3 * CHI][Hn];     // 12,288 B (total 49,152)

  const int b  = blockIdx.y, t0 = blockIdx.x * MROWS;
  const int tid = threadIdx.x;
  const int ng4 = tid & 63;         // cols ng4*4 .. +3
  const int mg  = tid >> 6;         // rows 8*mg .. +7 (one mg per wave)

  // ---- Stage A transposed: [chan][srow], srow = t-(t0-1) in 0..33 ----
  const float4* x4 = reinterpret_cast<const float4*>(x + (size_t)b * Tn * Hn);
  for (int idx = tid; idx < SROWS * (Hn / 4); idx += 256) {
    int row = idx >> 6, c4 = idx & 63;
    int t = t0 - 1 + row;
    float4 v = make_float4(0.f, 0.f, 0.f, 0.f);
    if (t >= 0 && t < Tn) v = x4[t * (Hn / 4) + c4];
    int i = c4 << 2;
    xsT[(i + 0) * SST + row] = v.x;
    xsT[(i + 1) * SST + row] = v.y;
    xsT[(i + 2) * SST + row] = v.z;
    xsT[(i + 3) * SST + row] = v.w;
  }

  // ---- Stage B chunk 0 directly (chunk rows: r = dt*CHI+ii, 6 rows) ----
  // Flat quad index fq in [0,384): dt=fq>>7, ii=(fq>>6)&1, q4=fq&63.
  const float4* w4 = reinterpret_cast<const float4*>(wP);
  {
    int fq = tid;                   // 0..255
    float4 v = w4[(((fq >> 7) << 8) + 0 + ((fq >> 6) & 1)) * 64 + (fq & 63)];
    *reinterpret_cast<float4*>(&bufB[0][fq >> 6][(fq & 63) * 4]) = v;
    if (tid < 128) {
      int f2 = tid + 256;           // 256..383
      float4 v2 = w4[(((f2 >> 7) << 8) + 0 + ((f2 >> 6) & 1)) * 64 + (f2 & 63)];
      *reinterpret_cast<float4*>(&bufB[0][f2 >> 6][(f2 & 63) * 4]) = v2;
    }
  }
  __syncthreads();

  float acc[8][4];
  #pragma unroll
  for (int rr = 0; rr < 8; ++rr)
    #pragma unroll
    for (int j = 0; j < 4; ++j) acc[rr][j] = 0.f;

  float4 p0; float4 p1;             // prefetch regs for next chunk
  #pragma unroll 1
  for (int c = 0; c < NCH; ++c) {
    const int cur = c & 1;
    const bool more = (c + 1 < NCH);
    if (more) {                     // issue-early: next chunk's global loads
      const int i0n = (c + 1) * CHI;
      int fq = tid;
      p0 = w4[(((fq >> 7) << 8) + i0n + ((fq >> 6) & 1)) * 64 + (fq & 63)];
      if (tid < 128) {
        int f2 = tid + 256;
        p1 = w4[(((f2 >> 7) << 8) + i0n + ((f2 >> 6) & 1)) * 64 + (f2 & 63)];
      }
    }
    #pragma unroll
    for (int ii = 0; ii < CHI; ++ii) {
      const int i = c * CHI + ii;
      const float* ap = &xsT[i * SST + 8 * mg];     // broadcast (same addr/wave)
      const float4 a01 = *reinterpret_cast<const float4*>(ap);
      const float4 a23 = *reinterpret_cast<const float4*>(ap + 4);
      const float2 a45 = *reinterpret_cast<const float2*>(ap + 8);
      const float a[10] = {a01.x, a01.y, a01.z, a01.w,
                           a23.x, a23.y, a23.z, a23.w, a45.x, a45.y};
      #pragma unroll
      for (int dt = 0; dt < 3; ++dt) {
        const float4 bq = *reinterpret_cast<const float4*>(
            &bufB[cur][dt * CHI + ii][ng4 * 4]);   // 64 lanes x 16B contiguous
        const float bb[4] = {bq.x, bq.y, bq.z, bq.w};
        #pragma unroll
        for (int rr = 0; rr < 8; ++rr)
          #pragma unroll
          for (int j = 0; j < 4; ++j)
            acc[rr][j] = fmaf(a[rr + dt], bb[j], acc[rr][j]);
      }
    }
    if (more) {                     // write-late into the other buffer
      *reinterpret_cast<float4*>(&bufB[cur ^ 1][tid >> 6][(tid & 63) * 4]) = p0;
      if (tid < 128) {
        int f2 = tid + 256;
        *reinterpret_cast<float4*>(&bufB[cur ^ 1][f2 >> 6][(f2 & 63) * 4]) = p1;
      }
    }
    __syncthreads();
  }

  // ---- Epilogue: +conv_b, ReLU, x lin_w^T over this thread's 4 cols ----
  float pem[8][4];
  #pragma unroll
  for (int rr = 0; rr < 8; ++rr)
    #pragma unroll
    for (int k = 0; k < 4; ++k) pem[rr][k] = 0.f;

  const int n0 = ng4 * 4;
  #pragma unroll
  for (int j = 0; j < 4; ++j) {
    const int n = n0 + j;
    const float cb = conv_b[n];
    const float l0 = lin_w[0 * Hn + n];
    const float l1 = lin_w[1 * Hn + n];
    const float l2 = lin_w[2 * Hn + n];
    const float l3 = lin_w[3 * Hn + n];
    #pragma unroll
    for (int rr = 0; rr < 8; ++rr) {
      float v = fmaxf(acc[rr][j] + cb, 0.f);
      pem[rr][0] = fmaf(v, l0, pem[rr][0]);
      pem[rr][1] = fmaf(v, l1, pem[rr][1]);
      pem[rr][2] = fmaf(v, l2, pem[rr][2]);
      pem[rr][3] = fmaf(v, l3, pem[rr][3]);
    }
  }
  // Reduce over all 64 lanes of the wave (cols 0..255)
  #pragma unroll
  for (int rr = 0; rr < 8; ++rr)
    #pragma unroll
    for (int k = 0; k < 4; ++k) {
      float v = pem[rr][k];
      v += __shfl_xor(v, 1);
      v += __shfl_xor(v, 2);
      v += __shfl_xor(v, 4);
      v += __shfl_xor(v, 8);
      v += __shfl_xor(v, 16);
      v += __shfl_xor(v, 32);
      pem[rr][k] = v;
    }
  if (ng4 == 0) {
    #pragma unroll
    for (int rr = 0; rr < 8; ++rr) {
      const int m = 8 * mg + rr;
      float4 o;
      o.x = pem[rr][0] + lin_b[0];
      o.y = pem[rr][1] + lin_b[1];
      o.z = pem[rr][2] + lin_b[2];
      o.w = pem[rr][3] + lin_b[3];
      *reinterpret_cast<float4*>(em + (size_t)(b * Tn + t0 + m) * 4) = o;
    }
  }
}

// byte-map composition c(k) = a(b(k))
__device__ __forceinline__ unsigned int compose_map(unsigned int a, unsigned int b) {
#if __has_builtin(__builtin_amdgcn_perm)
  return __builtin_amdgcn_perm(a, a, b);
#else
  unsigned int c = 0;
  #pragma unroll
  for (int k = 0; k < 4; ++k) {
    unsigned int sel = (b >> (8 * k)) & 0xffu;
    c |= ((a >> (8 * sel)) & 0xffu) << (8 * k);
  }
  return c;
#endif
}

// One Viterbi step. Value math: ns_k = (max_j (s_j + tr[j][k])) + e_k.
// Bitwise-identical to ref's max_j((s_j+tr)+e) by rounding monotonicity.
#define VSTEP(EV, T)                                                        \
  {                                                                         \
    sh[(T) - 1] = make_float4(s0, s1, s2, s3);                              \
    const float4 e_ = (EV);                                                 \
    float x0 = fmaxf(fmaxf(s0 + tr[0][0], s1 + tr[1][0]),                   \
                     fmaxf(s2 + tr[2][0], s3 + tr[3][0]));                  \
    float x1 = fmaxf(fmaxf(s0 + tr[0][1], s1 + tr[1][1]),                   \
                     fmaxf(s2 + tr[2][1], s3 + tr[3][1]));                  \
    float x2 = fmaxf(fmaxf(s0 + tr[0][2], s1 + tr[1][2]),                   \
                     fmaxf(s2 + tr[2][2], s3 + tr[3][2]));                  \
    float x3 = fmaxf(fmaxf(s0 + tr[0][3], s1 + tr[1][3]),                   \
                     fmaxf(s2 + tr[2][3], s3 + tr[3][3]));                  \
    s0 = x0 + e_.x; s1 = x1 + e_.y; s2 = x2 + e_.z; s3 = x3 + e_.w;         \
  }

// CRF Viterbi decode. Forward: serial scan on lane 0, 4x-unrolled with
// 4-deep register prefetch. Backtrace: 64 lanes rebuild argmax maps
// (exact per-candidate (s+tr)+e form, first-wins), v_perm suffix-scan.
__global__ __launch_bounds__(64) void viterbi_k(const float* __restrict__ em,
    const float* __restrict__ cstart, const float* __restrict__ cend,
    const float* __restrict__ ctrans, int* __restrict__ out) {
  __shared__ float4 se[Tn];          // emissions, 16 KB
  __shared__ float4 sh[Tn - 1];      // score vector BEFORE step t+1, 16 KB
  __shared__ int s_last;
  const int b = blockIdx.x, lane = threadIdx.x;
  const float4* e4 = reinterpret_cast<const float4*>(em + (size_t)b * Tn * Kn);
  for (int i = lane; i < Tn; i += 64) se[i] = e4[i];
  float tr[4][4];
  #pragma unroll
  for (int j = 0; j < 4; ++j)
    #pragma unroll
    for (int k = 0; k < 4; ++k) tr[j][k] = ctrans[j * 4 + k];
  __syncthreads();

  if (lane == 0) {
    float4 e0 = se[0];
    float s0 = cstart[0] + e0.x, s1 = cstart[1] + e0.y;
    float s2 = cstart[2] + e0.z, s3 = cstart[3] + e0.w;
    float4 eA = se[1], eB = se[2], eC = se[3], eD = se[4];
    for (int t = 1; t + 3 < Tn; t += 4) {
      const float4 f0 = eA, f1 = eB, f2 = eC, f3 = eD;
      if (t + 4 < Tn) eA = se[t + 4];
      if (t + 5 < Tn) eB = se[t + 5];
      if (t + 6 < Tn) eC = se[t + 6];
      if (t + 7 < Tn) eD = se[t + 7];
      VSTEP(f0, t);
      VSTEP(f1, t + 1);
      VSTEP(f2, t + 2);
      VSTEP(f3, t + 3);
    }
    VSTEP(eA, Tn - 3);
    VSTEP(eB, Tn - 2);
    VSTEP(eC, Tn - 1);
    s0 += cend[0]; s1 += cend[1]; s2 += cend[2]; s3 += cend[3];
    int tag = 0; float bf = s0;
    if (s1 > bf) { bf = s1; tag = 1; }
    if (s2 > bf) { bf = s2; tag = 2; }
    if (s3 > bf) { bf = s3; tag = 3; }
    s_last = tag;
  }
  __syncthreads();

  const unsigned int ID = 0x03020100u;
  unsigned int mloc[16];
  const int t0 = lane * 16;
  #pragma unroll
  for (int k = 0; k < 16; ++k) {
    const int t = t0 + k;
    if (t < Tn - 1) {
      const float4 s = sh[t];
      const float4 e = se[t + 1];
      const float sj[4] = {s.x, s.y, s.z, s.w};
      const float ev[4] = {e.x, e.y, e.z, e.w};
      unsigned int mw = 0;
      #pragma unroll
      for (int kk = 0; kk < 4; ++kk) {
        float best = (sj[0] + tr[0][kk]) + ev[kk];
        int bi = 0;
        #pragma unroll
        for (int j = 1; j < 4; ++j) {
          float cc = (sj[j] + tr[j][kk]) + ev[kk];
          if (cc > best) { best = cc; bi = j; }
        }
        mw |= (unsigned)bi << (8 * kk);
      }
      mloc[k] = mw;
    } else {
      mloc[k] = ID;
    }
  }
  unsigned int P = mloc[15];
  #pragma unroll
  for (int k = 14; k >= 0; --k) P = compose_map(mloc[k], P);
  #pragma unroll
  for (int d = 1; d < 64; d <<= 1) {
    unsigned int q = (unsigned int)__shfl_down((int)P, d);
    if (lane + d > 63) q = ID;
    P = compose_map(P, q);
  }
  unsigned int E = (unsigned int)__shfl_down((int)P, 1);  // exclusive suffix
  if (lane == 63) E = ID;
  const int last = s_last;
  unsigned int tag = (E >> (8 * last)) & 3u;
  int* ob = out + (size_t)b * Tn;
  #pragma unroll
  for (int k = 15; k >= 0; --k) {
    tag = (mloc[k] >> (8 * tag)) & 3u;
    ob[t0 + k] = (int)tag;
  }
}

extern "C" void kernel_launch(void* const* d_in, const int* in_sizes, int n_in,
                              void* d_out, int out_size, void* d_ws, size_t ws_size,
                              hipStream_t stream) {
  const float* x      = (const float*)d_in[0];
  const float* conv_w = (const float*)d_in[1];
  const float* conv_b = (const float*)d_in[2];
  const float* lin_w  = (const float*)d_in[3];
  const float* lin_b  = (const float*)d_in[4];
  const float* cstart = (const float*)d_in[5];
  const float* cend   = (const float*)d_in[6];
  const float* ctrans = (const float*)d_in[7];
  int* out = (int*)d_out;

  float* wP = (float*)d_ws;                      // 768*256 floats
  float* em = wP + 768 * 256;                    // 64*1024*4 floats

  pack_w_k<<<768, 256, 0, stream>>>(conv_w, wP);
  emis_k<<<dim3(Tn / MROWS, Bn), 256, 0, stream>>>(x, wP, conv_b, lin_w, lin_b, em);
  viterbi_k<<<Bn, 64, 0, stream>>>(em, cstart, cend, ctrans, out);
}